// Round 2
// baseline (605.717 us; speedup 1.0000x reference)
//
#include <hip/hip_runtime.h>

#define BS        64
#define W_TOTAL_C 2234368
#define B_TOTAL_C 3526

// ---------------------------------------------------------------------------
// zero the split-K completion counters (832 ints) — runs first every call
__global__ void zero_counters_kernel(int* __restrict__ c, int n) {
    int i = blockIdx.x * blockDim.x + threadIdx.x;
    if (i < n) c[i] = 0;
}

// ---------------------------------------------------------------------------
// fused split-K layer: partial matvec -> last block reduces + bias + act
// W[b][i][o] = wbase[b*W_TOTAL + WOFF + i*DOUT + o]
template<int DIN, int DOUT, int KC, int NK, int VEC, int BLK, int ACT,
         int WOFF, int BOFF>
__global__ __launch_bounds__(BLK)
void layer_fused(const float* __restrict__ hin,
                 const float* __restrict__ wbase,
                 const float* __restrict__ bias,
                 float* __restrict__ part,
                 int*   __restrict__ counters,   // pre-offset for this layer
                 float* __restrict__ hout)
{
    __shared__ float sh[KC];
    __shared__ int   sh_last;

    const int b   = blockIdx.z;
    const int ky  = blockIdx.y;
    const int k0  = ky * KC;
    const int tid = threadIdx.x;

    for (int i = tid; i < KC; i += BLK)
        sh[i] = hin[b * DIN + k0 + i];
    __syncthreads();

    const int  o      = (blockIdx.x * BLK + tid) * VEC;
    const bool active = (o < DOUT);

    float a[VEC];
    #pragma unroll
    for (int j = 0; j < VEC; ++j) a[j] = 0.f;

    if (active) {
        const float* wp = wbase + (size_t)b * W_TOTAL_C + WOFF
                                + (size_t)k0 * DOUT + o;
        #pragma unroll 8
        for (int i = 0; i < KC; ++i) {
            const float hv = sh[i];
            if (VEC == 4) {
                const float4 w = *reinterpret_cast<const float4*>(wp);
                a[0] = fmaf(hv, w.x, a[0]);
                a[1] = fmaf(hv, w.y, a[1]);
                a[2] = fmaf(hv, w.z, a[2]);
                a[3] = fmaf(hv, w.w, a[3]);
            } else {
                const float2 w = *reinterpret_cast<const float2*>(wp);
                a[0] = fmaf(hv, w.x, a[0]);
                a[1] = fmaf(hv, w.y, a[1]);
            }
            wp += DOUT;
        }
        float* pp = part + ((size_t)ky * BS + b) * DOUT + o;
        #pragma unroll
        for (int j = 0; j < VEC; ++j)
            __hip_atomic_store(pp + j, a[j], __ATOMIC_RELAXED,
                               __HIP_MEMORY_SCOPE_AGENT);
    }

    // elect the last-arriving block for this (ochunk, b) column group
    __threadfence();
    __syncthreads();
    if (tid == 0) {
        int old = __hip_atomic_fetch_add(&counters[blockIdx.x * BS + b], 1,
                                         __ATOMIC_ACQ_REL,
                                         __HIP_MEMORY_SCOPE_AGENT);
        sh_last = (old == NK - 1) ? 1 : 0;
    }
    __syncthreads();
    if (!sh_last) return;
    __threadfence();

    if (active) {
        #pragma unroll
        for (int j = 0; j < VEC; ++j) {
            float s = bias[b * B_TOTAL_C + BOFF + o + j];
            #pragma unroll
            for (int k = 0; k < NK; ++k)
                s += __hip_atomic_load(
                        part + ((size_t)k * BS + b) * DOUT + o + j,
                        __ATOMIC_RELAXED, __HIP_MEMORY_SCOPE_AGENT);
            float r;
            if (ACT == 0) r = s / (1.f + __expf(-s));   // silu
            else          r = tanhf(s);                  // tanh
            hout[b * DOUT + o + j] = r;
        }
    }
}

// ---------------------------------------------------------------------------
extern "C" void kernel_launch(void* const* d_in, const int* in_sizes, int n_in,
                              void* d_out, int out_size, void* d_ws, size_t ws_size,
                              hipStream_t stream)
{
    const float* x    = (const float*)d_in[0];   // [64][1862]
    const float* wts  = (const float*)d_in[1];   // [64][W_TOTAL]
    const float* bias = (const float*)d_in[2];   // [64][B_TOTAL]
    float* out = (float*)d_out;                  // [64][1862]

    // ws layout
    float* part = (float*)d_ws;                  // max 4*64*1862 = 476672 f
    float* hA   = part + 476672;                 // [64][512] max
    float* hB   = hA + BS * 512;                 // [64][512] max
    int*   cnt  = (int*)(hB + BS * 512);         // 832 ints

    const int NCNT = 832;   // L0..L4: 64 each (bases 0..256); L5: 8*64=512 (base 320)
    zero_counters_kernel<<<(NCNT + 255) / 256, 256, 0, stream>>>(cnt, NCNT);

    // L0: 1862 -> 512, silu
    layer_fused<1862, 512, 133, 14, 4, 128, 0,       0,    0>
        <<<dim3(1, 14, BS), 128, 0, stream>>>(x,  wts, bias, part, cnt +   0, hA);
    // L1: 512 -> 256, silu
    layer_fused< 512, 256,  64,  8, 4,  64, 0,  953344,  512>
        <<<dim3(1,  8, BS),  64, 0, stream>>>(hA, wts, bias, part, cnt +  64, hB);
    // L2: 256 -> 128, silu
    layer_fused< 256, 128,  32,  8, 2,  64, 0, 1084416,  768>
        <<<dim3(1,  8, BS),  64, 0, stream>>>(hB, wts, bias, part, cnt + 128, hA);
    // L3: 128 -> 256, silu
    layer_fused< 128, 256,  32,  4, 4,  64, 0, 1117184,  896>
        <<<dim3(1,  4, BS),  64, 0, stream>>>(hA, wts, bias, part, cnt + 192, hB);
    // L4: 256 -> 512, silu
    layer_fused< 256, 512,  32,  8, 4, 128, 0, 1149952, 1152>
        <<<dim3(1,  8, BS), 128, 0, stream>>>(hB, wts, bias, part, cnt + 256, hA);
    // L5: 512 -> 1862, tanh
    layer_fused< 512, 1862, 128, 4, 2, 128, 1, 1281024, 1664>
        <<<dim3(8,  4, BS), 128, 0, stream>>>(hA, wts, bias, part, cnt + 320, out);
}

// Round 3
// 121.886 us; speedup vs baseline: 4.9695x; 4.9695x over previous
//
#include <hip/hip_runtime.h>

#define BS        64
#define W_TOTAL_C 2234368
#define B_TOTAL_C 3526

__device__ __forceinline__ float silu_f(float v) {
    return v / (1.f + __expf(-v));
}

// ---------------------------------------------------------------------------
// One layer, split-K, NO cross-block sync:
//   - stage h-chunk into LDS; if PNK>0, h is reconstructed as
//     silu( sum_{k<PNK} prev_part[k][b][i] + prev_bias[i] )
//   - K-loop: a[j] += sh[i] * W[b][k0+i][o+j]   (coalesced float2 weight loads)
//   - if FINAL: write tanh(a + bias) straight to d_out
//     else:     write raw partial to this layer's slice (plain stores)
// Visibility across layers comes from kernel boundaries on the stream.
template<int DIN, int DOUT, int KC, int NK, int PNK, int VEC, int BLK,
         bool FINAL, int WOFF, int PBOFF, int FBOFF>
__global__ __launch_bounds__(BLK)
void layer_kernel(const float* __restrict__ hin,   // x (PNK==0) or prev partials
                  const float* __restrict__ wbase,
                  const float* __restrict__ bias,
                  float* __restrict__ outp)        // this layer's partials, or d_out
{
    __shared__ float sh[KC];

    const int b   = blockIdx.z;
    const int ky  = blockIdx.y;
    const int k0  = ky * KC;
    const int tid = threadIdx.x;

    // ---- stage h chunk (fuse prev layer's reduction + bias + silu) ----
    for (int i = tid; i < KC; i += BLK) {
        float s;
        if (PNK == 0) {
            s = hin[b * DIN + k0 + i];
        } else {
            s = bias[b * B_TOTAL_C + PBOFF + k0 + i];
            #pragma unroll
            for (int k = 0; k < PNK; ++k)
                s += hin[((size_t)k * BS + b) * DIN + k0 + i];
            s = silu_f(s);
        }
        sh[i] = s;
    }
    __syncthreads();

    const int  o      = (blockIdx.x * BLK + tid) * VEC;
    const bool active = (o < DOUT);

    float a0 = 0.f, a1 = 0.f;
    if (active) {
        const float* wp = wbase + (size_t)b * W_TOTAL_C + WOFF
                                + (size_t)k0 * DOUT + o;
        #pragma unroll 16
        for (int i = 0; i < KC; ++i) {
            const float hv = sh[i];
            const float2 w = *reinterpret_cast<const float2*>(wp);
            a0 = fmaf(hv, w.x, a0);
            a1 = fmaf(hv, w.y, a1);
            wp += DOUT;
        }
    }

    if (!active) return;

    if (FINAL) {
        float v0 = a0 + bias[b * B_TOTAL_C + FBOFF + o];
        outp[b * DOUT + o] = tanhf(v0);
        if (o + 1 < DOUT) {
            float v1 = a1 + bias[b * B_TOTAL_C + FBOFF + o + 1];
            outp[b * DOUT + o + 1] = tanhf(v1);
        }
    } else {
        float* pp = outp + ((size_t)ky * BS + b) * DOUT + o;
        pp[0] = a0;
        pp[1] = a1;
    }
}

// ---------------------------------------------------------------------------
extern "C" void kernel_launch(void* const* d_in, const int* in_sizes, int n_in,
                              void* d_out, int out_size, void* d_ws, size_t ws_size,
                              hipStream_t stream)
{
    const float* x    = (const float*)d_in[0];   // [64][1862]
    const float* wts  = (const float*)d_in[1];   // [64][W_TOTAL]
    const float* bias = (const float*)d_in[2];   // [64][B_TOTAL]
    float* out = (float*)d_out;                  // [64][1862]

    // partial slices (floats), all plain-store/plain-load, written before read
    float* p0 = (float*)d_ws;        // 7*64*512  = 229376
    float* p1 = p0 + 229376;         // 4*64*256  =  65536
    float* p2 = p1 + 65536;          // 4*64*128  =  32768
    float* p3 = p2 + 32768;          // 4*64*256  =  65536
    float* p4 = p3 + 65536;          // 4*64*512  = 131072  (total 524288 f = 2 MB)

    // L0: 1862 -> 512   (reads x; writes p0)       grid 2x7x64 = 896 blocks
    layer_kernel<1862, 512, 266, 7, 0, 2, 128, false,       0,    0,    0>
        <<<dim3(2, 7, BS), 128, 0, stream>>>(x, wts, bias, p0);
    // L1: 512 -> 256    (reduce p0 + silu; writes p1)  grid 1x4x64 = 256
    layer_kernel< 512, 256, 128, 4, 7, 2, 128, false,  953344,    0,    0>
        <<<dim3(1, 4, BS), 128, 0, stream>>>(p0, wts, bias, p1);
    // L2: 256 -> 128    (reduce p1; writes p2)          grid 1x4x64 = 256
    layer_kernel< 256, 128,  64, 4, 4, 2,  64, false, 1084416,  512,    0>
        <<<dim3(1, 4, BS),  64, 0, stream>>>(p1, wts, bias, p2);
    // L3: 128 -> 256    (reduce p2; writes p3)          grid 1x4x64 = 256
    layer_kernel< 128, 256,  32, 4, 4, 2, 128, false, 1117184,  768,    0>
        <<<dim3(1, 4, BS), 128, 0, stream>>>(p2, wts, bias, p3);
    // L4: 256 -> 512    (reduce p3; writes p4)          grid 2x4x64 = 512
    layer_kernel< 256, 512,  64, 4, 4, 2, 128, false, 1149952,  896,    0>
        <<<dim3(2, 4, BS), 128, 0, stream>>>(p3, wts, bias, p4);
    // L5: 512 -> 1862   (reduce p4; bias+tanh; writes d_out)  grid 8x1x64 = 512
    layer_kernel< 512, 1862, 512, 1, 4, 2, 128, true, 1281024, 1152, 1664>
        <<<dim3(8, 1, BS), 128, 0, stream>>>(p4, wts, bias, out);
}